// Round 8
// baseline (315.442 us; speedup 1.0000x reference)
//
#include <hip/hip_runtime.h>
#include <hip/hip_bf16.h>
#include <stdint.h>

// Problem constants (hard-coded: B=4, S=2048, D=1024, H=16, dk=64)
#define D_MODEL 1024
#define SEQ     2048
#define BATCH   4
#define NH      16
#define DKK     64
#define MROWS   (BATCH * SEQ)   // 8192

typedef unsigned short u16;
using bf16x8 = __attribute__((ext_vector_type(8))) __bf16;
using f32x4  = __attribute__((ext_vector_type(4))) float;

// float -> bf16 (RNE)
__device__ __forceinline__ u16 f2bf(float f) {
    union { float f; uint32_t u; } v; v.f = f;
    return (u16)((v.u + 0x7FFFu + ((v.u >> 16) & 1u)) >> 16);
}
// packed pair -> v_cvt_pk_bf16_f32 on gfx950
__device__ __forceinline__ uint32_t pk2bf(float a, float b) {
    union { __hip_bfloat162 h; uint32_t u; } v;
    v.h = __float22bfloat162_rn(float2{a, b});
    return v.u;
}

__device__ __forceinline__ float fast_exp2(float x) {
    float r; asm("v_exp_f32 %0, %1" : "=v"(r) : "v"(x)); return r;
}
__device__ __forceinline__ float fast_rcp(float x) {
    float r; asm("v_rcp_f32 %0, %1" : "=v"(r) : "v"(x)); return r;
}

// async global->LDS, 16B per lane; LDS dest wave-uniform base (+lane*16 implicit)
__device__ __forceinline__ void gl_lds16(const u16* g, u16* l) {
    __builtin_amdgcn_global_load_lds(
        (__attribute__((address_space(1))) void*)(const_cast<u16*>(g)),
        (__attribute__((address_space(3))) void*)l, 16, 0, 0);
}

// ---- GEMM staging swizzle (32-u16 LDS rows): kills 8-way b128 conflicts ----
__device__ __forceinline__ int stage_col8(int lane) {
    return (((lane & 3) ^ ((lane >> 3) & 3)) * 8);
}
__device__ __forceinline__ int frag_off(int row, int quad, int l15) {
    return row * 32 + ((quad ^ ((l15 >> 1) & 3)) * 8);
}

// ---- flash staging swizzle (64-u16 LDS rows, 8 granules/row) ----
// LDS[r][slot] = Global[r][slot ^ (r&7)]; per gl_lds16 instr lane -> row
// i*8+(lane>>3), slot lane&7 => source granule (lane&7)^((lane>>3)&7).
__device__ __forceinline__ int fstage_g8(int lane) {
    return (((lane & 7) ^ ((lane >> 3) & 7)) * 8);
}

// XOR-swizzled 128x128 u16 epilogue tile (qkv): element (o, n) -> u16 index.
__device__ __forceinline__ int swz(int o, int n) {
    const int pos = ((n >> 3) ^ (o & 15)) ^ (((o >> 4) & 1) << 2);
    return o * 128 + (pos << 3) + (n & 7);
}
__device__ __forceinline__ int swzg(int o, int gn) {
    const int pos = (gn ^ (o & 15)) ^ (((o >> 4) & 1) << 2);
    return o * 128 + (pos << 3);
}

// ---------------- fused fp32 -> bf16 convert (all 7 tensors) ----------------
__global__ __launch_bounds__(256) void cvt_all(const float* __restrict__ a,
                                               const float* __restrict__ b,
                                               const float* __restrict__ c,
                                               const float* __restrict__ wq,
                                               const float* __restrict__ wk,
                                               const float* __restrict__ wv,
                                               const float* __restrict__ wp,
                                               u16* __restrict__ da, u16* __restrict__ db,
                                               u16* __restrict__ dc, u16* __restrict__ dq,
                                               u16* __restrict__ dk, u16* __restrict__ dv,
                                               u16* __restrict__ dp) {
    const int i = blockIdx.x * 256 + threadIdx.x;       // 3*2^21 + 4*2^18 float4
    const float* s; u16* d; int off;
    if (i < 3 * (1 << 21)) {
        const int sel = i >> 21; off = i & ((1 << 21) - 1);
        s = (sel == 0) ? a : (sel == 1) ? b : c;
        d = (sel == 0) ? da : (sel == 1) ? db : dc;
    } else {
        const int j = i - 3 * (1 << 21);
        const int sel = j >> 18; off = j & ((1 << 18) - 1);
        s = (sel == 0) ? wq : (sel == 1) ? wk : (sel == 2) ? wv : wp;
        d = (sel == 0) ? dq : (sel == 1) ? dk : (sel == 2) ? dv : dp;
    }
    float4 v = ((const float4*)s)[off];
    uint2 o;
    o.x = pk2bf(v.x, v.y); o.y = pk2bf(v.z, v.w);
    ((uint2*)d)[off] = o;
}

// ---------------- fused QKV GEMM (unchanged from R7: 131k conflicts) ----------------
__global__ __launch_bounds__(256, 3) void gemm_qkv(const u16* __restrict__ XQ,
                                                   const u16* __restrict__ XK,
                                                   const u16* __restrict__ XV,
                                                   const u16* __restrict__ WQ,
                                                   const u16* __restrict__ WK,
                                                   const u16* __restrict__ WV,
                                                   u16* __restrict__ Qo,
                                                   u16* __restrict__ Ko,
                                                   u16* __restrict__ Vto) {
    constexpr int K = 1024, N = 1024;
    __shared__ __align__(16) u16 smem[16384];
    u16* ldsA = smem;
    u16* ldsB = smem + 8192;
    u16* ldsT = smem;

    const int which = blockIdx.x >> 9;
    const int inner = blockIdx.x & 511;
    const u16* A  = (which == 0) ? XQ : (which == 1) ? XK : XV;
    const u16* Bw = (which == 0) ? WQ : (which == 1) ? WK : WV;

    const int t = threadIdx.x;
    const int w = t >> 6, lane = t & 63;
    const int quad = lane >> 4, l15 = lane & 15;
    const int x = inner & 7, j = inner >> 3;
    const int bm = x * 8 + (j >> 3), bn = j & 7;
    const int wm = (w >> 1) * 64, wn = (w & 1) * 64;

    const u16* Ab = A  + (size_t)bm * 128 * K;
    const u16* Bb = Bw + (size_t)bn * 128 * K;
    const int srow  = lane >> 2;
    const int sc8   = stage_col8(lane);

    f32x4 acc[4][4];
    #pragma unroll
    for (int i = 0; i < 4; ++i)
        #pragma unroll
        for (int jj = 0; jj < 4; ++jj)
            acc[i][jj] = f32x4{0.f, 0.f, 0.f, 0.f};

    #pragma unroll
    for (int i = 0; i < 2; ++i) {
        const int c = w * 2 + i;
        gl_lds16(Ab + (size_t)(c * 16 + srow) * K + sc8, &ldsA[c * 512]);
        gl_lds16(Bb + (size_t)(c * 16 + srow) * K + sc8, &ldsB[c * 512]);
    }

    int cur = 0;
    for (int k0 = 0; k0 < K; k0 += 32) {
        __syncthreads();
        if (k0 + 32 < K) {
            const int nxt = cur ^ 1;
            #pragma unroll
            for (int i = 0; i < 2; ++i) {
                const int c = w * 2 + i;
                gl_lds16(Ab + (size_t)(c * 16 + srow) * K + k0 + 32 + sc8, &ldsA[nxt * 4096 + c * 512]);
                gl_lds16(Bb + (size_t)(c * 16 + srow) * K + k0 + 32 + sc8, &ldsB[nxt * 4096 + c * 512]);
            }
        }

        bf16x8 afr[4], bfr[4];
        #pragma unroll
        for (int i = 0; i < 4; ++i)
            afr[i] = *(const bf16x8*)&ldsA[cur * 4096 + frag_off(wm + i * 16 + l15, quad, l15)];
        #pragma unroll
        for (int jj = 0; jj < 4; ++jj)
            bfr[jj] = *(const bf16x8*)&ldsB[cur * 4096 + frag_off(wn + jj * 16 + l15, quad, l15)];

        #pragma unroll
        for (int i = 0; i < 4; ++i)
            #pragma unroll
            for (int jj = 0; jj < 4; ++jj)
                acc[i][jj] = __builtin_amdgcn_mfma_f32_16x16x32_bf16(afr[i], bfr[jj], acc[i][jj], 0, 0, 0);
        cur ^= 1;
    }

    __syncthreads();

    if (which < 2) {
        u16* outb = which ? Ko : Qo;
        #pragma unroll
        for (int i = 0; i < 4; ++i)
            #pragma unroll
            for (int jj = 0; jj < 4; ++jj)
                #pragma unroll
                for (int r = 0; r < 4; ++r)
                    ldsT[swz(wm + i * 16 + quad * 4 + r, wn + jj * 16 + l15)] = f2bf(acc[i][jj][r]);
        __syncthreads();
        const int rr = t >> 1, half = t & 1;
        u16* dstg = outb + (size_t)(bm * 128 + rr) * N + bn * 128;
        #pragma unroll
        for (int k = 0; k < 8; ++k) {
            const int gn = half * 8 + k;
            *(uint4*)(dstg + gn * 8) = *(const uint4*)&ldsT[swzg(rr, gn)];
        }
    } else {
        #pragma unroll
        for (int i = 0; i < 4; ++i)
            #pragma unroll
            for (int jj = 0; jj < 4; ++jj)
                #pragma unroll
                for (int r = 0; r < 4; ++r)
                    ldsT[swz(wn + jj * 16 + l15, wm + i * 16 + quad * 4 + r)] = f2bf(acc[i][jj][r]);
        __syncthreads();
        const int c = t >> 1, half = t & 1;
        const int colg = bn * 128 + c;
        const int hh = colg >> 6, dd = colg & 63;
        const int bb = bm >> 4;
        const int s0 = (bm * 128) & 2047;
        u16* dstg = Vto + (size_t)((bb * NH + hh) * DKK + dd) * SEQ + s0;
        #pragma unroll
        for (int k = 0; k < 8; ++k) {
            const int gn = half * 8 + k;
            *(uint4*)(dstg + gn * 8) = *(const uint4*)&ldsT[swzg(c, gn)];
        }
    }
}

// ---------------- final projection GEMM: 128x128 tiles (qkv-proven structure) ----------------
__global__ __launch_bounds__(256, 3) void gemm_proj(const u16* __restrict__ A,
                                                    const u16* __restrict__ Bw,
                                                    float* __restrict__ outf,
                                                    const float* __restrict__ bias) {
    constexpr int K = 1024, N = 1024;
    __shared__ __align__(16) u16 smem[16384];
    u16* ldsA = smem;
    u16* ldsB = smem + 8192;

    const int t = threadIdx.x;
    const int w = t >> 6, lane = t & 63;
    const int quad = lane >> 4, l15 = lane & 15;
    const int x = blockIdx.x & 7, j = blockIdx.x >> 3;
    const int bm = x * 8 + (j >> 3), bn = j & 7;
    const int wm = (w >> 1) * 64, wn = (w & 1) * 64;

    const u16* Ab = A  + (size_t)bm * 128 * K;
    const u16* Bb = Bw + (size_t)bn * 128 * K;
    const int srow  = lane >> 2;
    const int sc8   = stage_col8(lane);

    f32x4 acc[4][4];
    #pragma unroll
    for (int i = 0; i < 4; ++i)
        #pragma unroll
        for (int jj = 0; jj < 4; ++jj)
            acc[i][jj] = f32x4{0.f, 0.f, 0.f, 0.f};

    #pragma unroll
    for (int i = 0; i < 2; ++i) {
        const int c = w * 2 + i;
        gl_lds16(Ab + (size_t)(c * 16 + srow) * K + sc8, &ldsA[c * 512]);
        gl_lds16(Bb + (size_t)(c * 16 + srow) * K + sc8, &ldsB[c * 512]);
    }

    int cur = 0;
    for (int k0 = 0; k0 < K; k0 += 32) {
        __syncthreads();
        if (k0 + 32 < K) {
            const int nxt = cur ^ 1;
            #pragma unroll
            for (int i = 0; i < 2; ++i) {
                const int c = w * 2 + i;
                gl_lds16(Ab + (size_t)(c * 16 + srow) * K + k0 + 32 + sc8, &ldsA[nxt * 4096 + c * 512]);
                gl_lds16(Bb + (size_t)(c * 16 + srow) * K + k0 + 32 + sc8, &ldsB[nxt * 4096 + c * 512]);
            }
        }

        bf16x8 afr[4], bfr[4];
        #pragma unroll
        for (int i = 0; i < 4; ++i)
            afr[i] = *(const bf16x8*)&ldsA[cur * 4096 + frag_off(wm + i * 16 + l15, quad, l15)];
        #pragma unroll
        for (int jj = 0; jj < 4; ++jj)
            bfr[jj] = *(const bf16x8*)&ldsB[cur * 4096 + frag_off(wn + jj * 16 + l15, quad, l15)];

        #pragma unroll
        for (int i = 0; i < 4; ++i)
            #pragma unroll
            for (int jj = 0; jj < 4; ++jj)
                acc[i][jj] = __builtin_amdgcn_mfma_f32_16x16x32_bf16(afr[i], bfr[jj], acc[i][jj], 0, 0, 0);
        cur ^= 1;
    }

    #pragma unroll
    for (int i = 0; i < 4; ++i)
        #pragma unroll
        for (int jj = 0; jj < 4; ++jj)
            #pragma unroll
            for (int r = 0; r < 4; ++r) {
                const int row = bm * 128 + wm + i * 16 + quad * 4 + r;
                const int col = bn * 128 + wn + jj * 16 + l15;
                outf[(size_t)row * N + col] = acc[i][jj][r] + bias[col];
            }
}

// ---------------- causal flash attention v8: s-split, barrier-free ----------------
// Block = 64 q rows (all waves share q). Wave w owns s-tiles {w, w+4, ...}:
// stages its OWN 16KB K/V (granule-swizzled) and syncs with its OWN
// s_waitcnt vmcnt(0) — NO __syncthreads in the K-loop. Max-free softmax =>
// per-wave partial O/l just add; one cross-wave LDS reduction at the end.
// kf/vf fragments read once per tile (was 4x).
__global__ __launch_bounds__(256, 2) void flash_attn(const u16* __restrict__ Qb,
                                                     const u16* __restrict__ Kb,
                                                     const u16* __restrict__ Vt,
                                                     u16* __restrict__ O) {
    __shared__ __align__(16) u16 ldsKV[8 * 4096];  // [w] K tiles | [4+w] V tiles: 64KB
    __shared__ __align__(16) u16 ldsP[4 * 2048];   // per-wave [2 gl][16 q][16 gran x 4]: 16KB

    const int t = threadIdx.x;
    const int w = t >> 6, lane = t & 63;
    const int quad = lane >> 4, l15 = lane & 15;
    const int bh = blockIdx.x & 63;
    const int qt = 31 - (blockIdx.x >> 6);      // heavy blocks first
    const int b = bh >> 4, h = bh & 15;
    const int q0 = qt * 64;
    const int ntiles = qt + 1;                  // s-tiles 0..qt (64-aligned diag)

    const int g8 = fstage_g8(lane);
    const int r8 = lane >> 3;                   // staging row within 8-row group
    const size_t kbase = (size_t)b * SEQ * D_MODEL + h * DKK;
    const size_t vbase = (size_t)(bh * DKK) * SEQ;

    u16* myK = &ldsKV[w * 4096];
    u16* myV = &ldsKV[(4 + w) * 4096];
    u16* PwS = &ldsP[w * 2048];

    // Q B-frags (n=q on l15, k=d on quad*8+j), 4 q-sets x 2 k-halves
    bf16x8 qf[4][2];
    #pragma unroll
    for (int g = 0; g < 4; ++g) {
        const u16* Qrow = Qb + (size_t)(b * SEQ + q0 + g * 16 + l15) * D_MODEL + h * DKK;
        qf[g][0] = *(const bf16x8*)(Qrow + quad * 8);
        qf[g][1] = *(const bf16x8*)(Qrow + 32 + quad * 8);
    }

    f32x4 o_acc[4][4];
    #pragma unroll
    for (int g = 0; g < 4; ++g)
        #pragma unroll
        for (int nt = 0; nt < 4; ++nt) o_acc[g][nt] = f32x4{0.f, 0.f, 0.f, 0.f};
    float l_i[4] = {0.f, 0.f, 0.f, 0.f};

    const float C2 = 0.18033688f;   // log2(e) / sqrt(dk)

    for (int tile = w; tile < ntiles; tile += 4) {
        const int s0 = tile * 64;

        // ---- stage this wave's K and V tile (granule-swizzled 128B rows) ----
        #pragma unroll
        for (int i = 0; i < 8; ++i)
            gl_lds16(Kb + kbase + (size_t)(s0 + i * 8 + r8) * D_MODEL + g8, &myK[i * 512]);
        #pragma unroll
        for (int i = 0; i < 8; ++i)
            gl_lds16(Vt + vbase + (size_t)(i * 8 + r8) * SEQ + s0 + g8, &myV[i * 512]);
        asm volatile("s_waitcnt vmcnt(0)" ::: "memory");   // per-wave only!

        // ---- S^T = K Q^T for all 4 q-sets; kf read once ----
        f32x4 sc[4][4];
        #pragma unroll
        for (int g = 0; g < 4; ++g)
            #pragma unroll
            for (int jt = 0; jt < 4; ++jt) sc[g][jt] = f32x4{0.f, 0.f, 0.f, 0.f};
        #pragma unroll
        for (int ks = 0; ks < 2; ++ks)
            #pragma unroll
            for (int jt = 0; jt < 4; ++jt) {
                bf16x8 kf = *(const bf16x8*)&myK[(jt * 16 + l15) * 64 + (((ks * 4 + quad) ^ (l15 & 7)) << 3)];
                #pragma unroll
                for (int g = 0; g < 4; ++g)
                    sc[g][jt] = __builtin_amdgcn_mfma_f32_16x16x32_bf16(kf, qf[g][ks], sc[g][jt], 0, 0, 0);
            }

        // ---- causal mask: only the diagonal tile (s0 == q0) ----
        if (tile == ntiles - 1) {
            #pragma unroll
            for (int g = 0; g < 4; ++g)
                #pragma unroll
                for (int jt = 0; jt < 4; ++jt)
                    #pragma unroll
                    for (int r = 0; r < 4; ++r)
                        if (jt * 16 + quad * 4 + r > g * 16 + l15) sc[g][jt][r] = -3.0e38f;
        }

        // ---- softmax + PV in two g-pair passes (ldsP stays 4KB/wave) ----
        #pragma unroll
        for (int gp = 0; gp < 2; ++gp) {
            #pragma unroll
            for (int gl = 0; gl < 2; ++gl) {
                const int g = gp * 2 + gl;
                float tsum = 0.f;
                #pragma unroll
                for (int jt = 0; jt < 4; ++jt) {
                    float p[4];
                    #pragma unroll
                    for (int r = 0; r < 4; ++r) {
                        p[r] = fast_exp2(sc[g][jt][r] * C2);
                        tsum += p[r];
                    }
                    const int pos = (4 * jt + quad) ^ l15;
                    uint2 pk;
                    pk.x = pk2bf(p[0], p[1]);
                    pk.y = pk2bf(p[2], p[3]);
                    *(uint2*)&PwS[gl * 1024 + l15 * 64 + pos * 4] = pk;
                }
                tsum += __shfl_xor(tsum, 16);
                tsum += __shfl_xor(tsum, 32);
                l_i[g] += tsum;
            }

            asm volatile("s_waitcnt lgkmcnt(0)" ::: "memory");

            #pragma unroll
            for (int ks = 0; ks < 2; ++ks) {
                const int gg = 8 * ks + 2 * quad;
                union { bf16x8 v; uint2 u[2]; } pu[2];
                #pragma unroll
                for (int gl = 0; gl < 2; ++gl) {
                    pu[gl].u[0] = *(const uint2*)&PwS[gl * 1024 + l15 * 64 + ((gg) ^ l15) * 4];
                    pu[gl].u[1] = *(const uint2*)&PwS[gl * 1024 + l15 * 64 + ((gg + 1) ^ l15) * 4];
                }
                #pragma unroll
                for (int nt = 0; nt < 4; ++nt) {
                    bf16x8 vf = *(const bf16x8*)&myV[(nt * 16 + l15) * 64 + (((ks * 4 + quad) ^ (l15 & 7)) << 3)];
                    #pragma unroll
                    for (int gl = 0; gl < 2; ++gl)
                        o_acc[gp * 2 + gl][nt] = __builtin_amdgcn_mfma_f32_16x16x32_bf16(pu[gl].v, vf, o_acc[gp * 2 + gl][nt], 0, 0, 0);
                }
            }
        }
    }

    // ---- cross-wave reduction: O = sum_w O_w, l = sum_w l_w ----
    __syncthreads();                       // all waves done with their K/V LDS
    float* ldsO = (float*)ldsKV;           // [w][64 q][64 d] fp32 = 64KB
    float* ldsL = (float*)ldsP;            // [w*1024 + q]
    #pragma unroll
    for (int g = 0; g < 4; ++g) {
        #pragma unroll
        for (int nt = 0; nt < 4; ++nt)
            #pragma unroll
            for (int r = 0; r < 4; ++r) {
                const int q = g * 16 + quad * 4 + r;
                ldsO[w * 4096 + q * 64 + nt * 16 + l15] = o_acc[g][nt][r];
            }
        if (quad == 0) ldsL[w * 1024 + g * 16 + l15] = l_i[g];
    }
    __syncthreads();

    // 256 threads: q = t>>2 (64 rows), dseg = (t&3)*16 -> 16 outputs/thread
    const int q = t >> 2, dseg = (t & 3) * 16;
    float accv[16];
    #pragma unroll
    for (int e = 0; e < 16; ++e) accv[e] = 0.f;
    #pragma unroll
    for (int w4 = 0; w4 < 4; ++w4) {
        #pragma unroll
        for (int ee = 0; ee < 4; ++ee) {
            const f32x4 v = *(const f32x4*)&ldsO[w4 * 4096 + q * 64 + dseg + ee * 4];
            accv[ee * 4 + 0] += v[0]; accv[ee * 4 + 1] += v[1];
            accv[ee * 4 + 2] += v[2]; accv[ee * 4 + 3] += v[3];
        }
    }
    const float ltot = ldsL[q] + ldsL[1024 + q] + ldsL[2048 + q] + ldsL[3072 + q];
    const float rli = fast_rcp(ltot);
    uint32_t pk[8];
    #pragma unroll
    for (int e = 0; e < 8; ++e)
        pk[e] = pk2bf(accv[e * 2] * rli, accv[e * 2 + 1] * rli);
    u16* dst = O + (size_t)(b * SEQ + q0 + q) * D_MODEL + h * DKK + dseg;
    *(uint4*)dst       = *(const uint4*)&pk[0];
    *(uint4*)(dst + 8) = *(const uint4*)&pk[4];
}

// ---------------- host launch ----------------
extern "C" void kernel_launch(void* const* d_in, const int* in_sizes, int n_in,
                              void* d_out, int out_size, void* d_ws, size_t ws_size,
                              hipStream_t stream) {
    const float* q_in = (const float*)d_in[0];
    const float* k_in = (const float*)d_in[1];
    const float* v_in = (const float*)d_in[2];
    const float* Wq   = (const float*)d_in[3];
    const float* Wk   = (const float*)d_in[4];
    const float* Wv   = (const float*)d_in[5];
    const float* Wp   = (const float*)d_in[6];
    const float* bp   = (const float*)d_in[7];
    float* out = (float*)d_out;

    char* ws = (char*)d_ws;
    u16* XQ  = (u16*)(ws + (size_t)0);           // 16MB; reused as AttnOut
    u16* XK  = (u16*)(ws + ((size_t)16 << 20));
    u16* XV  = (u16*)(ws + ((size_t)32 << 20));
    u16* WQb = (u16*)(ws + ((size_t)48 << 20));
    u16* WKb = (u16*)(ws + ((size_t)50 << 20));
    u16* WVb = (u16*)(ws + ((size_t)52 << 20));
    u16* WPb = (u16*)(ws + ((size_t)54 << 20));
    u16* Qb  = (u16*)(ws + ((size_t)56 << 20));
    u16* Kb  = (u16*)(ws + ((size_t)72 << 20));
    u16* Vtb = (u16*)(ws + ((size_t)88 << 20));  // total 104 MB

    const int n4 = 3 * (1 << 21) + 4 * (1 << 18);
    cvt_all<<<n4 / 256, 256, 0, stream>>>(q_in, k_in, v_in, Wq, Wk, Wv, Wp,
                                          XQ, XK, XV, WQb, WKb, WVb, WPb);

    gemm_qkv<<<1536, 256, 0, stream>>>(XQ, XK, XV, WQb, WKb, WVb, Qb, Kb, Vtb);

    flash_attn<<<64 * (SEQ / 64), 256, 0, stream>>>(Qb, Kb, Vtb, XQ);

    gemm_proj<<<512, 256, 0, stream>>>(XQ, WPb, out, bp);
}